// Round 1
// baseline (599.817 us; speedup 1.0000x reference)
//
#include <hip/hip_runtime.h>

// RG-LRU fused kernel set for MI355X (gfx950)
// B=4, T=4096, D=1024
// Pipeline:
//   prep:       fp32->bf16 conversion of x, W_r, W_i; decay = 8*softplus(Lambda)
//   gemm_gates: bf16 MFMA dual-GEMM (r,i logits) + fused gate math
//               -> a (fp32, ws), gx (fp32, d_out)
//   scan1:      per-chunk (prod a, local h)
//   combine:    sequential over 64 chunks -> h_start per chunk, h_T to d_out tail
//   scan2:      per-chunk rescan with correct h_start, in-place in d_out

#define B_ 4
#define T_ 4096
#define D_ 1024
#define BT_ (B_ * T_)          // 16384
#define NC_ 64                 // chunks over T
#define L_ (T_ / NC_)          // 64 steps per chunk

typedef float v4f __attribute__((ext_vector_type(4)));
typedef __bf16 v8bf __attribute__((ext_vector_type(8)));

__device__ inline unsigned short f2bf(float f) {
    unsigned int u = __float_as_uint(f);
    u += 0x7FFFu + ((u >> 16) & 1u);   // round-to-nearest-even
    return (unsigned short)(u >> 16);
}

__device__ inline ushort4 f2bf4(float4 v) {
    return make_ushort4(f2bf(v.x), f2bf(v.y), f2bf(v.z), f2bf(v.w));
}

// ---------------------------------------------------------------- prep
__global__ void prep_kernel(const float4* __restrict__ x4,
                            const float4* __restrict__ wr4,
                            const float4* __restrict__ wi4,
                            const float* __restrict__ lam,
                            ushort4* __restrict__ xb4,
                            ushort4* __restrict__ wrb4,
                            ushort4* __restrict__ wib4,
                            float* __restrict__ decay) {
    const int n = gridDim.x * blockDim.x;
    const int tid = blockIdx.x * blockDim.x + threadIdx.x;
    const int nx4 = (BT_ * D_) / 4;      // 4,194,304
    const int nw4 = (D_ * D_) / 4;       // 262,144
    for (int i = tid; i < nx4; i += n) xb4[i] = f2bf4(x4[i]);
    for (int i = tid; i < nw4; i += n) {
        wrb4[i] = f2bf4(wr4[i]);
        wib4[i] = f2bf4(wi4[i]);
    }
    for (int i = tid; i < D_; i += n) {
        float sp = log1pf(expf(lam[i]));     // softplus, Lambda < 0 so stable
        decay[i] = 8.0f * sp;
    }
}

// ---------------------------------------------------------------- gemm + gates
// Block = 256 threads = 4 waves. Tile: M=64 (16 rows/wave), N=64 cols (d).
// grid = (BT/64, D/64) = (256, 16)
// MFMA 16x16x32 bf16: A-frag lane l holds A[l&15][8*(l>>4)+e], e=0..7
//                     B-frag lane l holds B[8*(l>>4)+e][l&15]
//                     C/D: col = lane&15, row = (lane>>4)*4 + reg   [m89/m91]
__global__ __launch_bounds__(256) void gemm_gates(
    const unsigned short* __restrict__ xb,
    const unsigned short* __restrict__ wrb,
    const unsigned short* __restrict__ wib,
    const float* __restrict__ br,
    const float* __restrict__ bi,
    const float* __restrict__ decay,
    const float* __restrict__ x,
    float* __restrict__ a_buf,
    float* __restrict__ gx_out) {
    const int w = threadIdx.x >> 6;    // wave 0..3
    const int l = threadIdx.x & 63;
    const int lr = l & 15;
    const int lg = l >> 4;
    const int rowbase = blockIdx.x * 64 + w * 16;
    const int colbase = blockIdx.y * 64;

    v4f accr[4], acci[4];
#pragma unroll
    for (int cg = 0; cg < 4; ++cg)
#pragma unroll
        for (int j = 0; j < 4; ++j) { accr[cg][j] = 0.0f; acci[cg][j] = 0.0f; }

    const unsigned short* xrow = xb + (rowbase + lr) * D_ + lg * 8;

    for (int k0 = 0; k0 < D_; k0 += 32) {
        v8bf af = *reinterpret_cast<const v8bf*>(xrow + k0);
#pragma unroll
        for (int cg = 0; cg < 4; ++cg) {
            const int col = colbase + cg * 16 + lr;
            v8bf brf = *reinterpret_cast<const v8bf*>(wrb + col * D_ + lg * 8 + k0);
            v8bf bif = *reinterpret_cast<const v8bf*>(wib + col * D_ + lg * 8 + k0);
            accr[cg] = __builtin_amdgcn_mfma_f32_16x16x32_bf16(af, brf, accr[cg], 0, 0, 0);
            acci[cg] = __builtin_amdgcn_mfma_f32_16x16x32_bf16(af, bif, acci[cg], 0, 0, 0);
        }
    }

#pragma unroll
    for (int cg = 0; cg < 4; ++cg) {
        const int gcol = colbase + cg * 16 + lr;
        const float brv = br[gcol];
        const float biv = bi[gcol];
        const float dec = decay[gcol];
#pragma unroll
        for (int r = 0; r < 4; ++r) {
            const int grow = rowbase + lg * 4 + r;
            const int o = grow * D_ + gcol;
            const float zr = accr[cg][r] + brv;
            const float zi = acci[cg][r] + biv;
            const float rg = 1.0f / (1.0f + __expf(-zr));
            const float ig = 1.0f / (1.0f + __expf(-zi));
            const float av = __expf(-dec * rg);
            const float sc = sqrtf(fmaxf(1.0f - av * av, 0.0f));
            const float xv = x[o];
            a_buf[o] = av;
            gx_out[o] = sc * (ig * xv);
        }
    }
}

// ---------------------------------------------------------------- scan pass 1
// idx = (b*NC + c)*D + d ; computes P = prod(a) over chunk, H = local h (start 0)
__global__ __launch_bounds__(256) void scan1(const float* __restrict__ a,
                                             const float* __restrict__ gx,
                                             float* __restrict__ P,
                                             float* __restrict__ H) {
    const int idx = blockIdx.x * 256 + threadIdx.x;   // [0, B*NC*D)
    const int d = idx & (D_ - 1);
    const int c = (idx >> 10) & (NC_ - 1);
    const int b = idx >> 16;
    const int base = (b * T_ + c * L_) * D_ + d;
    float p = 1.0f, h = 0.0f;
    for (int t = 0; t < L_; ++t) {
        const float at = a[base + t * D_];
        const float g = gx[base + t * D_];
        p *= at;
        h = at * h + g;
    }
    P[idx] = p;
    H[idx] = h;
}

// ---------------------------------------------------------------- combine
// Sequential over NC chunks per (b,d). Writes h_start per chunk + final h_T.
__global__ __launch_bounds__(256) void combine(const float* __restrict__ P,
                                               const float* __restrict__ H,
                                               const float* __restrict__ h0,
                                               float* __restrict__ hstart,
                                               float* __restrict__ hT) {
    const int idx = blockIdx.x * 256 + threadIdx.x;   // [0, B*D)
    const int d = idx & (D_ - 1);
    const int b = idx >> 10;
    float h = h0[b * D_ + d];
    for (int c = 0; c < NC_; ++c) {
        const int o = (b * NC_ + c) * D_ + d;
        hstart[o] = h;
        h = P[o] * h + H[o];
    }
    hT[b * D_ + d] = h;
}

// ---------------------------------------------------------------- scan pass 2
// Rescan each chunk with correct h_start; gx is in `out`, overwritten in place.
__global__ __launch_bounds__(256) void scan2(const float* __restrict__ a,
                                             float* __restrict__ out,
                                             const float* __restrict__ hstart) {
    const int idx = blockIdx.x * 256 + threadIdx.x;   // [0, B*NC*D)
    const int d = idx & (D_ - 1);
    const int c = (idx >> 10) & (NC_ - 1);
    const int b = idx >> 16;
    const int base = (b * T_ + c * L_) * D_ + d;
    float h = hstart[idx];
    for (int t = 0; t < L_; ++t) {
        const int o = base + t * D_;
        h = a[o] * h + out[o];
        out[o] = h;
    }
}

// ---------------------------------------------------------------- launch
extern "C" void kernel_launch(void* const* d_in, const int* in_sizes, int n_in,
                              void* d_out, int out_size, void* d_ws, size_t ws_size,
                              hipStream_t stream) {
    const float* x   = (const float*)d_in[0];
    const float* h0  = (const float*)d_in[1];
    const float* Wr  = (const float*)d_in[2];
    const float* br  = (const float*)d_in[3];
    const float* Wi  = (const float*)d_in[4];
    const float* bi  = (const float*)d_in[5];
    const float* lam = (const float*)d_in[6];
    float* out = (float*)d_out;

    char* ws = (char*)d_ws;
    unsigned short* xb  = (unsigned short*)ws; ws += (size_t)BT_ * D_ * 2;   // 33.5 MB
    unsigned short* wrb = (unsigned short*)ws; ws += (size_t)D_ * D_ * 2;    //  2 MB
    unsigned short* wib = (unsigned short*)ws; ws += (size_t)D_ * D_ * 2;    //  2 MB
    float* decay  = (float*)ws;  ws += (size_t)D_ * 4;                       //  4 KB
    float* a_buf  = (float*)ws;  ws += (size_t)BT_ * D_ * 4;                 // 67 MB
    float* P      = (float*)ws;  ws += (size_t)B_ * NC_ * D_ * 4;            //  1 MB
    float* Hc     = (float*)ws;  ws += (size_t)B_ * NC_ * D_ * 4;            //  1 MB
    float* hstart = (float*)ws;                                              //  1 MB

    prep_kernel<<<2048, 256, 0, stream>>>(
        (const float4*)x, (const float4*)Wr, (const float4*)Wi, lam,
        (ushort4*)xb, (ushort4*)wrb, (ushort4*)wib, decay);

    gemm_gates<<<dim3(BT_ / 64, D_ / 64), 256, 0, stream>>>(
        xb, wrb, wib, br, bi, decay, x, a_buf, out);

    scan1<<<(B_ * NC_ * D_) / 256, 256, 0, stream>>>(a_buf, out, P, Hc);

    combine<<<(B_ * D_) / 256, 256, 0, stream>>>(P, Hc, h0, hstart, out + (size_t)BT_ * D_);

    scan2<<<(B_ * NC_ * D_) / 256, 256, 0, stream>>>(a_buf, out, hstart);
}

// Round 2
// 254.426 us; speedup vs baseline: 2.3575x; 2.3575x over previous
//
#include <hip/hip_runtime.h>

// RG-LRU fused kernel set for MI355X (gfx950)
// B=4, T=4096, D=1024
// R2: gemm_gates rebuilt on the m97 structure: 128x128 tile, BK=32,
//     global_load_lds(16B) staging of A/Br/Bi, 2-barrier K-loop,
//     4 waves x (64x64 quadrant) x dual accumulators (r,i).

#define B_ 4
#define T_ 4096
#define D_ 1024
#define BT_ (B_ * T_)          // 16384
#define NC_ 64                 // chunks over T
#define L_ (T_ / NC_)          // 64 steps per chunk

#define BM 128
#define BN 128
#define BK 32

typedef float v4f __attribute__((ext_vector_type(4)));
typedef __bf16 v8bf __attribute__((ext_vector_type(8)));
typedef unsigned int u32;

__device__ inline unsigned short f2bf(float f) {
    unsigned int u = __float_as_uint(f);
    u += 0x7FFFu + ((u >> 16) & 1u);   // round-to-nearest-even
    return (unsigned short)(u >> 16);
}

__device__ inline ushort4 f2bf4(float4 v) {
    return make_ushort4(f2bf(v.x), f2bf(v.y), f2bf(v.z), f2bf(v.w));
}

// async global->LDS, 16B per lane; lds base must be wave-uniform
__device__ inline void gload16(const void* g, void* l) {
    __builtin_amdgcn_global_load_lds(
        (const __attribute__((address_space(1))) u32*)g,
        (__attribute__((address_space(3))) u32*)l, 16, 0, 0);
}

// ---------------------------------------------------------------- prep
__global__ void prep_kernel(const float4* __restrict__ x4,
                            const float4* __restrict__ wr4,
                            const float4* __restrict__ wi4,
                            const float* __restrict__ lam,
                            ushort4* __restrict__ xb4,
                            ushort4* __restrict__ wrb4,
                            ushort4* __restrict__ wib4,
                            float* __restrict__ decay) {
    const int n = gridDim.x * blockDim.x;
    const int tid = blockIdx.x * blockDim.x + threadIdx.x;
    const int nx4 = (BT_ * D_) / 4;      // 4,194,304
    const int nw4 = (D_ * D_) / 4;       // 262,144
    for (int i = tid; i < nx4; i += n) xb4[i] = f2bf4(x4[i]);
    for (int i = tid; i < nw4; i += n) {
        wrb4[i] = f2bf4(wr4[i]);
        wib4[i] = f2bf4(wi4[i]);
    }
    for (int i = tid; i < D_; i += n) {
        float sp = log1pf(expf(lam[i]));     // softplus, Lambda < 0 so stable
        decay[i] = 8.0f * sp;
    }
}

// ---------------------------------------------------------------- gemm + gates
// Block = 256 threads = 4 waves, tile 128x128, BK=32.
// Wave w -> quadrant (wr=w>>1, wc=w&1): rows wr*64.., cols wc*64..
// MFMA 16x16x32 bf16: A-frag lane l holds A[l&15][8*(l>>4)+e]
//                     B-frag lane l holds B[8*(l>>4)+e][l&15]
//                     C/D: col = lane&15, row = (lane>>4)*4 + reg   [m89/m91]
__global__ __launch_bounds__(256) void gemm_gates(
    const unsigned short* __restrict__ xb,
    const unsigned short* __restrict__ wrb,
    const unsigned short* __restrict__ wib,
    const float* __restrict__ br,
    const float* __restrict__ bi,
    const float* __restrict__ decay,
    const float* __restrict__ x,
    float* __restrict__ a_buf,
    float* __restrict__ gx_out) {
    __shared__ __align__(16) unsigned short sA[BM * BK];   // 8 KB
    __shared__ __align__(16) unsigned short sBr[BN * BK];  // 8 KB
    __shared__ __align__(16) unsigned short sBi[BN * BK];  // 8 KB

    const int tid = threadIdx.x;
    const int lane = tid & 63;
    const int wave = tid >> 6;
    const int wr = wave >> 1;
    const int wc = wave & 1;
    const int lr = lane & 15;
    const int lg = lane >> 4;

    const int rowbase = blockIdx.x * BM;
    const int colbase = blockIdx.y * BN;

    // staging map: thread t covers tile bytes [t*16, t*16+16) (issue0, rows 0..63)
    // and [4096 + t*16, ...) (issue1, rows 64..127). Tile row stride = 64 B.
    const int s_row = tid >> 2;          // 0..63
    const int s_col = (tid & 3) * 8;     // k element offset

    const unsigned short* gA0  = xb  + (size_t)(rowbase + s_row) * D_ + s_col;
    const unsigned short* gA1  = gA0 + (size_t)64 * D_;
    const unsigned short* gBr0 = wrb + (size_t)(colbase + s_row) * D_ + s_col;
    const unsigned short* gBr1 = gBr0 + (size_t)64 * D_;
    const unsigned short* gBi0 = wib + (size_t)(colbase + s_row) * D_ + s_col;
    const unsigned short* gBi1 = gBi0 + (size_t)64 * D_;

    // wave-uniform LDS bases (dest = base + lane*16)
    char* lA0  = (char*)sA  + wave * 1024;
    char* lA1  = lA0 + 4096;
    char* lBr0 = (char*)sBr + wave * 1024;
    char* lBr1 = lBr0 + 4096;
    char* lBi0 = (char*)sBi + wave * 1024;
    char* lBi1 = lBi0 + 4096;

    v4f accr[4][4], acci[4][4];
#pragma unroll
    for (int mi = 0; mi < 4; ++mi)
#pragma unroll
        for (int ni = 0; ni < 4; ++ni)
#pragma unroll
            for (int j = 0; j < 4; ++j) { accr[mi][ni][j] = 0.0f; acci[mi][ni][j] = 0.0f; }

    for (int k0 = 0; k0 < D_; k0 += BK) {
        gload16(gA0  + k0, lA0);
        gload16(gA1  + k0, lA1);
        gload16(gBr0 + k0, lBr0);
        gload16(gBr1 + k0, lBr1);
        gload16(gBi0 + k0, lBi0);
        gload16(gBi1 + k0, lBi1);
        __syncthreads();   // drains vmcnt + barrier

        v8bf af[4], brf[4], bif[4];
#pragma unroll
        for (int mi = 0; mi < 4; ++mi)
            af[mi] = *reinterpret_cast<const v8bf*>(sA + (wr * 64 + mi * 16 + lr) * BK + lg * 8);
#pragma unroll
        for (int ni = 0; ni < 4; ++ni) {
            brf[ni] = *reinterpret_cast<const v8bf*>(sBr + (wc * 64 + ni * 16 + lr) * BK + lg * 8);
            bif[ni] = *reinterpret_cast<const v8bf*>(sBi + (wc * 64 + ni * 16 + lr) * BK + lg * 8);
        }
#pragma unroll
        for (int mi = 0; mi < 4; ++mi)
#pragma unroll
            for (int ni = 0; ni < 4; ++ni) {
                accr[mi][ni] = __builtin_amdgcn_mfma_f32_16x16x32_bf16(af[mi], brf[ni], accr[mi][ni], 0, 0, 0);
                acci[mi][ni] = __builtin_amdgcn_mfma_f32_16x16x32_bf16(af[mi], bif[ni], acci[mi][ni], 0, 0, 0);
            }
        __syncthreads();   // all reads done before next stage overwrites
    }

    // epilogue: gates
#pragma unroll
    for (int ni = 0; ni < 4; ++ni) {
        const int gcol = colbase + wc * 64 + ni * 16 + lr;
        const float brv = br[gcol];
        const float biv = bi[gcol];
        const float dec = decay[gcol];
#pragma unroll
        for (int mi = 0; mi < 4; ++mi) {
#pragma unroll
            for (int r = 0; r < 4; ++r) {
                const int grow = rowbase + wr * 64 + mi * 16 + lg * 4 + r;
                const size_t o = (size_t)grow * D_ + gcol;
                const float zr = accr[mi][ni][r] + brv;
                const float zi = acci[mi][ni][r] + biv;
                const float rg = 1.0f / (1.0f + __expf(-zr));
                const float ig = 1.0f / (1.0f + __expf(-zi));
                const float av = __expf(-dec * rg);
                const float sc = sqrtf(fmaxf(1.0f - av * av, 0.0f));
                const float xv = x[o];
                a_buf[o] = av;
                gx_out[o] = sc * (ig * xv);
            }
        }
    }
}

// ---------------------------------------------------------------- scan pass 1
__global__ __launch_bounds__(256) void scan1(const float* __restrict__ a,
                                             const float* __restrict__ gx,
                                             float* __restrict__ P,
                                             float* __restrict__ H) {
    const int idx = blockIdx.x * 256 + threadIdx.x;   // [0, B*NC*D)
    const int d = idx & (D_ - 1);
    const int c = (idx >> 10) & (NC_ - 1);
    const int b = idx >> 16;
    const size_t base = ((size_t)b * T_ + c * L_) * D_ + d;
    float p = 1.0f, h = 0.0f;
    for (int t = 0; t < L_; ++t) {
        const float at = a[base + (size_t)t * D_];
        const float g = gx[base + (size_t)t * D_];
        p *= at;
        h = at * h + g;
    }
    P[idx] = p;
    H[idx] = h;
}

// ---------------------------------------------------------------- combine
__global__ __launch_bounds__(256) void combine(const float* __restrict__ P,
                                               const float* __restrict__ H,
                                               const float* __restrict__ h0,
                                               float* __restrict__ hstart,
                                               float* __restrict__ hT) {
    const int idx = blockIdx.x * 256 + threadIdx.x;   // [0, B*D)
    const int d = idx & (D_ - 1);
    const int b = idx >> 10;
    float h = h0[b * D_ + d];
    for (int c = 0; c < NC_; ++c) {
        const int o = (b * NC_ + c) * D_ + d;
        hstart[o] = h;
        h = P[o] * h + H[o];
    }
    hT[b * D_ + d] = h;
}

// ---------------------------------------------------------------- scan pass 2
__global__ __launch_bounds__(256) void scan2(const float* __restrict__ a,
                                             float* __restrict__ out,
                                             const float* __restrict__ hstart) {
    const int idx = blockIdx.x * 256 + threadIdx.x;   // [0, B*NC*D)
    const int d = idx & (D_ - 1);
    const int c = (idx >> 10) & (NC_ - 1);
    const int b = idx >> 16;
    const size_t base = ((size_t)b * T_ + c * L_) * D_ + d;
    float h = hstart[idx];
    for (int t = 0; t < L_; ++t) {
        const size_t o = base + (size_t)t * D_;
        h = a[o] * h + out[o];
        out[o] = h;
    }
}

// ---------------------------------------------------------------- launch
extern "C" void kernel_launch(void* const* d_in, const int* in_sizes, int n_in,
                              void* d_out, int out_size, void* d_ws, size_t ws_size,
                              hipStream_t stream) {
    const float* x   = (const float*)d_in[0];
    const float* h0  = (const float*)d_in[1];
    const float* Wr  = (const float*)d_in[2];
    const float* br  = (const float*)d_in[3];
    const float* Wi  = (const float*)d_in[4];
    const float* bi  = (const float*)d_in[5];
    const float* lam = (const float*)d_in[6];
    float* out = (float*)d_out;

    char* ws = (char*)d_ws;
    unsigned short* xb  = (unsigned short*)ws; ws += (size_t)BT_ * D_ * 2;   // 33.5 MB
    unsigned short* wrb = (unsigned short*)ws; ws += (size_t)D_ * D_ * 2;    //  2 MB
    unsigned short* wib = (unsigned short*)ws; ws += (size_t)D_ * D_ * 2;    //  2 MB
    float* decay  = (float*)ws;  ws += (size_t)D_ * 4;                       //  4 KB
    float* a_buf  = (float*)ws;  ws += (size_t)BT_ * D_ * 4;                 // 67 MB
    float* P      = (float*)ws;  ws += (size_t)B_ * NC_ * D_ * 4;            //  1 MB
    float* Hc     = (float*)ws;  ws += (size_t)B_ * NC_ * D_ * 4;            //  1 MB
    float* hstart = (float*)ws;                                              //  1 MB

    prep_kernel<<<2048, 256, 0, stream>>>(
        (const float4*)x, (const float4*)Wr, (const float4*)Wi, lam,
        (ushort4*)xb, (ushort4*)wrb, (ushort4*)wib, decay);

    gemm_gates<<<dim3(BT_ / BM, D_ / BN), 256, 0, stream>>>(
        xb, wrb, wib, br, bi, decay, x, a_buf, out);

    scan1<<<(B_ * NC_ * D_) / 256, 256, 0, stream>>>(a_buf, out, P, Hc);

    combine<<<(B_ * D_) / 256, 256, 0, stream>>>(P, Hc, h0, hstart, out + (size_t)BT_ * D_);

    scan2<<<(B_ * NC_ * D_) / 256, 256, 0, stream>>>(a_buf, out, hstart);
}

// Round 3
// 226.128 us; speedup vs baseline: 2.6525x; 1.1251x over previous
//
#include <hip/hip_runtime.h>

// RG-LRU fused kernel set for MI355X (gfx950)
// B=4, T=4096, D=1024
// R3: gemm_gates: 128x128 tile, BK=32, DOUBLE-BUFFERED global_load_lds staging
//     (prefetch-first, one barrier per K-step), XOR-swizzled LDS
//     (pre-swizzled global source + swizzled ds_read) -> conflict-free b128 reads.

#define B_ 4
#define T_ 4096
#define D_ 1024
#define BT_ (B_ * T_)          // 16384
#define NC_ 64                 // chunks over T
#define L_ (T_ / NC_)          // 64 steps per chunk

#define BM 128
#define BN 128
#define BK 32

#define TILE_BYTES 8192        // 128 rows x 64 B
#define BUF_BYTES  24576       // A + Br + Bi

typedef float v4f __attribute__((ext_vector_type(4)));
typedef __bf16 v8bf __attribute__((ext_vector_type(8)));
typedef unsigned int u32;

__device__ inline unsigned short f2bf(float f) {
    unsigned int u = __float_as_uint(f);
    u += 0x7FFFu + ((u >> 16) & 1u);   // round-to-nearest-even
    return (unsigned short)(u >> 16);
}

__device__ inline ushort4 f2bf4(float4 v) {
    return make_ushort4(f2bf(v.x), f2bf(v.y), f2bf(v.z), f2bf(v.w));
}

// async global->LDS, 16B per lane; lds base must be wave-uniform
__device__ inline void gload16(const void* g, void* l) {
    __builtin_amdgcn_global_load_lds(
        (const __attribute__((address_space(1))) u32*)g,
        (__attribute__((address_space(3))) u32*)l, 16, 0, 0);
}

// ---------------------------------------------------------------- prep
__global__ void prep_kernel(const float4* __restrict__ x4,
                            const float4* __restrict__ wr4,
                            const float4* __restrict__ wi4,
                            const float* __restrict__ lam,
                            ushort4* __restrict__ xb4,
                            ushort4* __restrict__ wrb4,
                            ushort4* __restrict__ wib4,
                            float* __restrict__ decay) {
    const int n = gridDim.x * blockDim.x;
    const int tid = blockIdx.x * blockDim.x + threadIdx.x;
    const int nx4 = (BT_ * D_) / 4;      // 4,194,304
    const int nw4 = (D_ * D_) / 4;       // 262,144
    for (int i = tid; i < nx4; i += n) xb4[i] = f2bf4(x4[i]);
    for (int i = tid; i < nw4; i += n) {
        wrb4[i] = f2bf4(wr4[i]);
        wib4[i] = f2bf4(wi4[i]);
    }
    for (int i = tid; i < D_; i += n) {
        float sp = log1pf(expf(lam[i]));     // softplus, Lambda < 0 so stable
        decay[i] = 8.0f * sp;
    }
}

// ---------------------------------------------------------------- gemm + gates
// Block = 256 threads = 4 waves, tile 128x128, BK=32, double-buffered.
// Swizzle: LDS[row][slot] holds G[row][slot ^ ((row>>1)&3)] (slot = 16B unit).
//   stage: thread t -> linear LDS byte t*16; global col = ((t&3)^((t>>3)&3))*8
//   read:  byte = row*64 + ((lg ^ ((row>>1)&3))*16)  -> 2 lanes/bank (free)
// MFMA 16x16x32 bf16 fragment maps per m89/m91.
__global__ __launch_bounds__(256) void gemm_gates(
    const unsigned short* __restrict__ xb,
    const unsigned short* __restrict__ wrb,
    const unsigned short* __restrict__ wib,
    const float* __restrict__ br,
    const float* __restrict__ bi,
    const float* __restrict__ decay,
    const float* __restrict__ x,
    float* __restrict__ a_buf,
    float* __restrict__ gx_out) {
    __shared__ __align__(16) char smem[2][BUF_BYTES];   // 48 KB

    const int tid = threadIdx.x;
    const int lane = tid & 63;
    const int wave = tid >> 6;
    const int wr = wave >> 1;
    const int wc = wave & 1;
    const int lr = lane & 15;
    const int lg = lane >> 4;

    const int rowbase = blockIdx.x * BM;
    const int colbase = blockIdx.y * BN;

    // ---- staging source (pre-swizzled global k-offset)
    const int s_row = tid >> 2;                               // 0..63
    const int s_col = (((tid & 3) ^ ((tid >> 3) & 3)) * 8);   // swizzled k element
    const unsigned short* gA0  = xb  + (size_t)(rowbase + s_row) * D_ + s_col;
    const unsigned short* gA1  = gA0 + (size_t)64 * D_;
    const unsigned short* gBr0 = wrb + (size_t)(colbase + s_row) * D_ + s_col;
    const unsigned short* gBr1 = gBr0 + (size_t)64 * D_;
    const unsigned short* gBi0 = wib + (size_t)(colbase + s_row) * D_ + s_col;
    const unsigned short* gBi1 = gBi0 + (size_t)64 * D_;

    // ---- wave-uniform LDS staging dests (dest = base + lane*16), per buffer
    const int woff = wave * 1024;

    // ---- swizzled ds_read byte offsets (within a buffer), precomputed
    int offA[4], offBr[4], offBi[4];
#pragma unroll
    for (int mi = 0; mi < 4; ++mi) {
        const int row = wr * 64 + mi * 16 + lr;
        offA[mi] = row * 64 + ((lg ^ ((row >> 1) & 3)) * 16);
    }
#pragma unroll
    for (int ni = 0; ni < 4; ++ni) {
        const int row = wc * 64 + ni * 16 + lr;
        const int o = row * 64 + ((lg ^ ((row >> 1) & 3)) * 16);
        offBr[ni] = TILE_BYTES + o;
        offBi[ni] = 2 * TILE_BYTES + o;
    }

    v4f accr[4][4], acci[4][4];
#pragma unroll
    for (int mi = 0; mi < 4; ++mi)
#pragma unroll
        for (int ni = 0; ni < 4; ++ni)
#pragma unroll
            for (int j = 0; j < 4; ++j) { accr[mi][ni][j] = 0.0f; acci[mi][ni][j] = 0.0f; }

#define STAGE(bufidx, k0)                                                   \
    do {                                                                    \
        char* b = smem[bufidx];                                             \
        gload16(gA0  + (k0), b + woff);                                     \
        gload16(gA1  + (k0), b + woff + 4096);                              \
        gload16(gBr0 + (k0), b + TILE_BYTES + woff);                        \
        gload16(gBr1 + (k0), b + TILE_BYTES + woff + 4096);                 \
        gload16(gBi0 + (k0), b + 2 * TILE_BYTES + woff);                    \
        gload16(gBi1 + (k0), b + 2 * TILE_BYTES + woff + 4096);             \
    } while (0)

#define COMPUTE(bufidx)                                                     \
    do {                                                                    \
        const char* b = smem[bufidx];                                       \
        v8bf af[4], brf[4], bif[4];                                         \
        _Pragma("unroll")                                                   \
        for (int mi = 0; mi < 4; ++mi)                                      \
            af[mi] = *reinterpret_cast<const v8bf*>(b + offA[mi]);          \
        _Pragma("unroll")                                                   \
        for (int ni = 0; ni < 4; ++ni) {                                    \
            brf[ni] = *reinterpret_cast<const v8bf*>(b + offBr[ni]);        \
            bif[ni] = *reinterpret_cast<const v8bf*>(b + offBi[ni]);        \
        }                                                                   \
        _Pragma("unroll")                                                   \
        for (int mi = 0; mi < 4; ++mi)                                      \
            _Pragma("unroll")                                               \
            for (int ni = 0; ni < 4; ++ni) {                                \
                accr[mi][ni] = __builtin_amdgcn_mfma_f32_16x16x32_bf16(     \
                    af[mi], brf[ni], accr[mi][ni], 0, 0, 0);                \
                acci[mi][ni] = __builtin_amdgcn_mfma_f32_16x16x32_bf16(     \
                    af[mi], bif[ni], acci[mi][ni], 0, 0, 0);                \
            }                                                               \
    } while (0)

    STAGE(0, 0);
    __syncthreads();                     // prologue drain

    for (int k0 = 0; k0 < D_; k0 += 64) {
        if (k0 + 32 < D_) STAGE(1, k0 + 32);   // prefetch FIRST (hides under compute)
        COMPUTE(0);
        __syncthreads();                        // drains prefetch vmcnt + read-done sync
        if (k0 + 64 < D_) STAGE(0, k0 + 64);
        COMPUTE(1);
        __syncthreads();
    }
#undef STAGE
#undef COMPUTE

    // epilogue: gates
#pragma unroll
    for (int ni = 0; ni < 4; ++ni) {
        const int gcol = colbase + wc * 64 + ni * 16 + lr;
        const float brv = br[gcol];
        const float biv = bi[gcol];
        const float dec = decay[gcol];
#pragma unroll
        for (int mi = 0; mi < 4; ++mi) {
#pragma unroll
            for (int r = 0; r < 4; ++r) {
                const int grow = rowbase + wr * 64 + mi * 16 + lg * 4 + r;
                const size_t o = (size_t)grow * D_ + gcol;
                const float zr = accr[mi][ni][r] + brv;
                const float zi = acci[mi][ni][r] + biv;
                const float rg = 1.0f / (1.0f + __expf(-zr));
                const float ig = 1.0f / (1.0f + __expf(-zi));
                const float av = __expf(-dec * rg);
                const float sc = sqrtf(fmaxf(1.0f - av * av, 0.0f));
                const float xv = x[o];
                a_buf[o] = av;
                gx_out[o] = sc * (ig * xv);
            }
        }
    }
}

// ---------------------------------------------------------------- scan pass 1
__global__ __launch_bounds__(256) void scan1(const float* __restrict__ a,
                                             const float* __restrict__ gx,
                                             float* __restrict__ P,
                                             float* __restrict__ H) {
    const int idx = blockIdx.x * 256 + threadIdx.x;   // [0, B*NC*D)
    const int d = idx & (D_ - 1);
    const int c = (idx >> 10) & (NC_ - 1);
    const int b = idx >> 16;
    const size_t base = ((size_t)b * T_ + c * L_) * D_ + d;
    float p = 1.0f, h = 0.0f;
    for (int t = 0; t < L_; ++t) {
        const float at = a[base + (size_t)t * D_];
        const float g = gx[base + (size_t)t * D_];
        p *= at;
        h = at * h + g;
    }
    P[idx] = p;
    H[idx] = h;
}

// ---------------------------------------------------------------- combine
__global__ __launch_bounds__(256) void combine(const float* __restrict__ P,
                                               const float* __restrict__ H,
                                               const float* __restrict__ h0,
                                               float* __restrict__ hstart,
                                               float* __restrict__ hT) {
    const int idx = blockIdx.x * 256 + threadIdx.x;   // [0, B*D)
    const int d = idx & (D_ - 1);
    const int b = idx >> 10;
    float h = h0[b * D_ + d];
    for (int c = 0; c < NC_; ++c) {
        const int o = (b * NC_ + c) * D_ + d;
        hstart[o] = h;
        h = P[o] * h + H[o];
    }
    hT[b * D_ + d] = h;
}

// ---------------------------------------------------------------- scan pass 2
__global__ __launch_bounds__(256) void scan2(const float* __restrict__ a,
                                             float* __restrict__ out,
                                             const float* __restrict__ hstart) {
    const int idx = blockIdx.x * 256 + threadIdx.x;   // [0, B*NC*D)
    const int d = idx & (D_ - 1);
    const int c = (idx >> 10) & (NC_ - 1);
    const int b = idx >> 16;
    const size_t base = ((size_t)b * T_ + c * L_) * D_ + d;
    float h = hstart[idx];
    for (int t = 0; t < L_; ++t) {
        const size_t o = base + (size_t)t * D_;
        h = a[o] * h + out[o];
        out[o] = h;
    }
}

// ---------------------------------------------------------------- launch
extern "C" void kernel_launch(void* const* d_in, const int* in_sizes, int n_in,
                              void* d_out, int out_size, void* d_ws, size_t ws_size,
                              hipStream_t stream) {
    const float* x   = (const float*)d_in[0];
    const float* h0  = (const float*)d_in[1];
    const float* Wr  = (const float*)d_in[2];
    const float* br  = (const float*)d_in[3];
    const float* Wi  = (const float*)d_in[4];
    const float* bi  = (const float*)d_in[5];
    const float* lam = (const float*)d_in[6];
    float* out = (float*)d_out;

    char* ws = (char*)d_ws;
    unsigned short* xb  = (unsigned short*)ws; ws += (size_t)BT_ * D_ * 2;   // 33.5 MB
    unsigned short* wrb = (unsigned short*)ws; ws += (size_t)D_ * D_ * 2;    //  2 MB
    unsigned short* wib = (unsigned short*)ws; ws += (size_t)D_ * D_ * 2;    //  2 MB
    float* decay  = (float*)ws;  ws += (size_t)D_ * 4;                       //  4 KB
    float* a_buf  = (float*)ws;  ws += (size_t)BT_ * D_ * 4;                 // 67 MB
    float* P      = (float*)ws;  ws += (size_t)B_ * NC_ * D_ * 4;            //  1 MB
    float* Hc     = (float*)ws;  ws += (size_t)B_ * NC_ * D_ * 4;            //  1 MB
    float* hstart = (float*)ws;                                              //  1 MB

    prep_kernel<<<2048, 256, 0, stream>>>(
        (const float4*)x, (const float4*)Wr, (const float4*)Wi, lam,
        (ushort4*)xb, (ushort4*)wrb, (ushort4*)wib, decay);

    gemm_gates<<<dim3(BT_ / BM, D_ / BN), 256, 0, stream>>>(
        xb, wrb, wib, br, bi, decay, x, a_buf, out);

    scan1<<<(B_ * NC_ * D_) / 256, 256, 0, stream>>>(a_buf, out, P, Hc);

    combine<<<(B_ * D_) / 256, 256, 0, stream>>>(P, Hc, h0, hstart, out + (size_t)BT_ * D_);

    scan2<<<(B_ * NC_ * D_) / 256, 256, 0, stream>>>(a_buf, out, hstart);
}

// Round 4
// 166.671 us; speedup vs baseline: 3.5988x; 1.3567x over previous
//
#include <hip/hip_runtime.h>

// RG-LRU fused kernel set for MI355X (gfx950)
// B=4, T=4096, D=1024
// R4: gemm_gates ported to the m201 8-phase template (adapted):
//     256M x 128d tile, B-tile = [Wr|Wi] 256 B-rows, BK=64, 8 waves,
//     4 phases/K-tile, counted vmcnt(2) (never 0 in steady state),
//     raw s_barrier, setprio around MFMA, XOR-swizzled LDS (row&7 on 16B slots),
//     fused gate epilogue (each wave holds both zr and zi for its 128x32 tile).

#define B_ 4
#define T_ 4096
#define D_ 1024
#define BT_ (B_ * T_)          // 16384
#define NC_ 64                 // chunks over T
#define L_ (T_ / NC_)          // 64 steps per chunk

#define BMR 256                // M rows per block
#define BNC 128                // d cols per block
#define BKT 64                 // K per tile
#define NT_ (D_ / BKT)         // 16 K-tiles
#define BUFB 65536             // bytes per LDS buffer (A 32K + B 32K)

typedef float v4f __attribute__((ext_vector_type(4)));
typedef __bf16 v8bf __attribute__((ext_vector_type(8)));
typedef unsigned int u32;

__device__ inline unsigned short f2bf(float f) {
    unsigned int u = __float_as_uint(f);
    u += 0x7FFFu + ((u >> 16) & 1u);   // round-to-nearest-even
    return (unsigned short)(u >> 16);
}

__device__ inline ushort4 f2bf4(float4 v) {
    return make_ushort4(f2bf(v.x), f2bf(v.y), f2bf(v.z), f2bf(v.w));
}

// async global->LDS, 16B per lane; lds base must be wave-uniform
__device__ inline void gload16(const void* g, void* l) {
    __builtin_amdgcn_global_load_lds(
        (const __attribute__((address_space(1))) u32*)g,
        (__attribute__((address_space(3))) u32*)l, 16, 0, 0);
}

// ---------------------------------------------------------------- prep
__global__ void prep_kernel(const float4* __restrict__ x4,
                            const float4* __restrict__ wr4,
                            const float4* __restrict__ wi4,
                            const float* __restrict__ lam,
                            ushort4* __restrict__ xb4,
                            ushort4* __restrict__ wrb4,
                            ushort4* __restrict__ wib4,
                            float* __restrict__ decay) {
    const int n = gridDim.x * blockDim.x;
    const int tid = blockIdx.x * blockDim.x + threadIdx.x;
    const int nx4 = (BT_ * D_) / 4;
    const int nw4 = (D_ * D_) / 4;
    for (int i = tid; i < nx4; i += n) xb4[i] = f2bf4(x4[i]);
    for (int i = tid; i < nw4; i += n) {
        wrb4[i] = f2bf4(wr4[i]);
        wib4[i] = f2bf4(wi4[i]);
    }
    for (int i = tid; i < D_; i += n) {
        float sp = log1pf(expf(lam[i]));
        decay[i] = 8.0f * sp;
    }
}

// ---------------------------------------------------------------- gemm + gates
// LDS layout per buffer: A region [row 0..255][slot 0..7 (16B)] linear, then
// B region same for 256 B-rows ([Wr d0..63 | Wi d0..63 | Wr d64..127 | Wi d64..127]).
// Swizzle: LDS slot s of row r holds global k-slot (s ^ (r&7)); staging uses
// pre-swizzled GLOBAL source (linear LDS dest), reads use swizzled addr.
// Wave (wr,wc): M rows wr*128+[0,128), d-cols colbase + wc*32 + [0,32), both r,i.
__global__ __launch_bounds__(512, 2) void gemm_gates(
    const unsigned short* __restrict__ xb,
    const unsigned short* __restrict__ wrb,
    const unsigned short* __restrict__ wib,
    const float* __restrict__ br,
    const float* __restrict__ bi,
    const float* __restrict__ decay,
    const float* __restrict__ x,
    float* __restrict__ a_buf,
    float* __restrict__ gx_out) {
    __shared__ __align__(16) char lds[2 * BUFB];   // 128 KB

    const int tid = threadIdx.x;
    const int lane = tid & 63;
    const int wave = tid >> 6;      // 0..7
    const int wr = wave >> 2;       // 0..1
    const int wc = wave & 3;        // 0..3
    const int lr = lane & 15;
    const int lg = lane >> 4;
    const int rowbase = blockIdx.x * BMR;
    const int colbase = blockIdx.y * BNC;

    // staging map: thread covers one 16B piece per gload16 issue
    const int srow = tid >> 3;                    // 0..63 within quarter
    const int kslot = (tid & 7) ^ (srow & 7);     // pre-swizzled global slot

    const unsigned short* gAq[4];
#pragma unroll
    for (int q = 0; q < 4; ++q)
        gAq[q] = xb + (size_t)(rowbase + q * 64 + srow) * D_ + kslot * 8;
    const unsigned short* gBq[4];
    gBq[0] = wrb + (size_t)(colbase + srow) * D_ + kslot * 8;
    gBq[1] = wib + (size_t)(colbase + srow) * D_ + kslot * 8;
    gBq[2] = wrb + (size_t)(colbase + 64 + srow) * D_ + kslot * 8;
    gBq[3] = wib + (size_t)(colbase + 64 + srow) * D_ + kslot * 8;

    // wave-uniform LDS staging dest bases (dest = base + lane*16)
#define STG_A(nb, q, kel) gload16(gAq[q] + (kel), lds + (nb) * BUFB + (q) * 8192 + wave * 1024)
#define STG_B(nb, q, kel) gload16(gBq[q] + (kel), lds + (nb) * BUFB + 32768 + (q) * 8192 + wave * 1024)

    const int bo = (wc & 1) * 32;       // within-strip col offset
    const int bstrip = wc >> 1;         // d-strip (0: d0..63, 1: d64..127)

    v4f ar[8][2], ai[8][2];
#pragma unroll
    for (int mi = 0; mi < 8; ++mi)
#pragma unroll
        for (int nf = 0; nf < 2; ++nf)
#pragma unroll
            for (int j = 0; j < 4; ++j) { ar[mi][nf][j] = 0.0f; ai[mi][nf][j] = 0.0f; }

    v8bf cbr[2], cbi[2];   // B fragments, persist MH0 -> MH1

    // ---- prologue: stage tile 0 into buf 0, full drain
    STG_A(0, 0, 0); STG_A(0, 1, 0); STG_A(0, 2, 0); STG_A(0, 3, 0);
    STG_B(0, 0, 0); STG_B(0, 1, 0); STG_B(0, 2, 0); STG_B(0, 3, 0);
    __builtin_amdgcn_sched_barrier(0);
    asm volatile("s_waitcnt vmcnt(0)");
    __builtin_amdgcn_s_barrier();

    // phase: ds_read subtile; stage next-tile quarters; counted vmcnt; barrier;
    //        setprio(1) 16 MFMA setprio(0); barrier.
#define PHASE(lb, KS, MH, PRECODE)                                              \
    do {                                                                        \
        if ((MH) == 0) {                                                        \
            _Pragma("unroll")                                                   \
            for (int nf = 0; nf < 2; ++nf) {                                    \
                const int brr = bstrip * 128 + bo + nf * 16 + lr;               \
                cbr[nf] = *(const v8bf*)((lb) + 32768 + brr * 128 +             \
                                         (((KS) * 4 + lg) ^ (brr & 7)) * 16);   \
                const int bri = brr + 64;                                       \
                cbi[nf] = *(const v8bf*)((lb) + 32768 + bri * 128 +             \
                                         (((KS) * 4 + lg) ^ (bri & 7)) * 16);   \
            }                                                                   \
        }                                                                       \
        v8bf af[4];                                                             \
        _Pragma("unroll")                                                       \
        for (int m4 = 0; m4 < 4; ++m4) {                                        \
            const int row = wr * 128 + ((MH) * 4 + m4) * 16 + lr;               \
            af[m4] = *(const v8bf*)((lb) + row * 128 +                          \
                                    (((KS) * 4 + lg) ^ (row & 7)) * 16);        \
        }                                                                       \
        PRECODE;                                                                \
        __builtin_amdgcn_sched_barrier(0);                                      \
        __builtin_amdgcn_s_barrier();                                           \
        __builtin_amdgcn_s_setprio(1);                                          \
        _Pragma("unroll")                                                       \
        for (int m4 = 0; m4 < 4; ++m4)                                          \
            _Pragma("unroll")                                                   \
            for (int nf = 0; nf < 2; ++nf) {                                    \
                ar[(MH) * 4 + m4][nf] = __builtin_amdgcn_mfma_f32_16x16x32_bf16( \
                    af[m4], cbr[nf], ar[(MH) * 4 + m4][nf], 0, 0, 0);           \
                ai[(MH) * 4 + m4][nf] = __builtin_amdgcn_mfma_f32_16x16x32_bf16( \
                    af[m4], cbi[nf], ai[(MH) * 4 + m4][nf], 0, 0, 0);           \
            }                                                                   \
        __builtin_amdgcn_s_setprio(0);                                          \
        __builtin_amdgcn_sched_barrier(0);                                      \
        __builtin_amdgcn_s_barrier();                                           \
    } while (0)

    for (int t = 0; t < NT_; ++t) {
        const int sw = t & 1;
        const int nb = sw ^ 1;
        const char* lb = lds + sw * BUFB;
        const int knext = (t + 1) * BKT;
        const bool more = (t + 1 < NT_);

        // P0 (ks0, mi 0-3): stage next Bq0,Bq1; vmcnt(2) covers this tile's Aq1/Aq3
        PHASE(lb, 0, 0,
              if (more) {
                  STG_B(nb, 0, knext); STG_B(nb, 1, knext);
                  __builtin_amdgcn_sched_barrier(0);
                  asm volatile("s_waitcnt vmcnt(2)");
              } else {
                  __builtin_amdgcn_sched_barrier(0);
                  asm volatile("s_waitcnt vmcnt(0)");
              });
        // P1 (ks0, mi 4-7): stage next Bq2,Bq3
        PHASE(lb, 0, 1,
              if (more) { STG_B(nb, 2, knext); STG_B(nb, 3, knext); });
        // P2 (ks1, mi 0-3): stage next Aq0,Aq2
        PHASE(lb, 1, 0,
              if (more) { STG_A(nb, 0, knext); STG_A(nb, 2, knext); });
        // P3 (ks1, mi 4-7): stage next Aq1,Aq3; vmcnt(2) covers next tile's P0 needs
        PHASE(lb, 1, 1,
              if (more) {
                  STG_A(nb, 1, knext); STG_A(nb, 3, knext);
                  __builtin_amdgcn_sched_barrier(0);
                  asm volatile("s_waitcnt vmcnt(2)");
              });
    }
#undef PHASE
#undef STG_A
#undef STG_B

    // ---- fused gate epilogue: wave owns rows [rowbase+wr*128, +128) x
    //      cols [colbase+wc*32, +32), with both zr (ar) and zi (ai).
#pragma unroll
    for (int nf = 0; nf < 2; ++nf) {
        const int gcol = colbase + wc * 32 + nf * 16 + lr;
        const float brv = br[gcol];
        const float biv = bi[gcol];
        const float dec = decay[gcol];
#pragma unroll
        for (int mi = 0; mi < 8; ++mi) {
#pragma unroll
            for (int rr = 0; rr < 4; ++rr) {
                const int grow = rowbase + wr * 128 + mi * 16 + lg * 4 + rr;
                const size_t o = (size_t)grow * D_ + gcol;
                const float zr = ar[mi][nf][rr] + brv;
                const float zi = ai[mi][nf][rr] + biv;
                const float rg = 1.0f / (1.0f + __expf(-zr));
                const float ig = 1.0f / (1.0f + __expf(-zi));
                const float av = __expf(-dec * rg);
                const float sc = sqrtf(fmaxf(1.0f - av * av, 0.0f));
                const float xv = x[o];
                a_buf[o] = av;
                gx_out[o] = sc * (ig * xv);
            }
        }
    }
}

// ---------------------------------------------------------------- scan pass 1
__global__ __launch_bounds__(256) void scan1(const float* __restrict__ a,
                                             const float* __restrict__ gx,
                                             float* __restrict__ P,
                                             float* __restrict__ H) {
    const int idx = blockIdx.x * 256 + threadIdx.x;   // [0, B*NC*D)
    const int d = idx & (D_ - 1);
    const int c = (idx >> 10) & (NC_ - 1);
    const int b = idx >> 16;
    const size_t base = ((size_t)b * T_ + c * L_) * D_ + d;
    float p = 1.0f, h = 0.0f;
    for (int t = 0; t < L_; ++t) {
        const float at = a[base + (size_t)t * D_];
        const float g = gx[base + (size_t)t * D_];
        p *= at;
        h = at * h + g;
    }
    P[idx] = p;
    H[idx] = h;
}

// ---------------------------------------------------------------- combine
__global__ __launch_bounds__(256) void combine(const float* __restrict__ P,
                                               const float* __restrict__ H,
                                               const float* __restrict__ h0,
                                               float* __restrict__ hstart,
                                               float* __restrict__ hT) {
    const int idx = blockIdx.x * 256 + threadIdx.x;   // [0, B*D)
    const int d = idx & (D_ - 1);
    const int b = idx >> 10;
    float h = h0[b * D_ + d];
    for (int c = 0; c < NC_; ++c) {
        const int o = (b * NC_ + c) * D_ + d;
        hstart[o] = h;
        h = P[o] * h + H[o];
    }
    hT[b * D_ + d] = h;
}

// ---------------------------------------------------------------- scan pass 2
__global__ __launch_bounds__(256) void scan2(const float* __restrict__ a,
                                             float* __restrict__ out,
                                             const float* __restrict__ hstart) {
    const int idx = blockIdx.x * 256 + threadIdx.x;   // [0, B*NC*D)
    const int d = idx & (D_ - 1);
    const int c = (idx >> 10) & (NC_ - 1);
    const int b = idx >> 16;
    const size_t base = ((size_t)b * T_ + c * L_) * D_ + d;
    float h = hstart[idx];
    for (int t = 0; t < L_; ++t) {
        const size_t o = base + (size_t)t * D_;
        h = a[o] * h + out[o];
        out[o] = h;
    }
}

// ---------------------------------------------------------------- launch
extern "C" void kernel_launch(void* const* d_in, const int* in_sizes, int n_in,
                              void* d_out, int out_size, void* d_ws, size_t ws_size,
                              hipStream_t stream) {
    const float* x   = (const float*)d_in[0];
    const float* h0  = (const float*)d_in[1];
    const float* Wr  = (const float*)d_in[2];
    const float* br  = (const float*)d_in[3];
    const float* Wi  = (const float*)d_in[4];
    const float* bi  = (const float*)d_in[5];
    const float* lam = (const float*)d_in[6];
    float* out = (float*)d_out;

    char* ws = (char*)d_ws;
    unsigned short* xb  = (unsigned short*)ws; ws += (size_t)BT_ * D_ * 2;   // 33.5 MB
    unsigned short* wrb = (unsigned short*)ws; ws += (size_t)D_ * D_ * 2;    //  2 MB
    unsigned short* wib = (unsigned short*)ws; ws += (size_t)D_ * D_ * 2;    //  2 MB
    float* decay  = (float*)ws;  ws += (size_t)D_ * 4;                       //  4 KB
    float* a_buf  = (float*)ws;  ws += (size_t)BT_ * D_ * 4;                 // 67 MB
    float* P      = (float*)ws;  ws += (size_t)B_ * NC_ * D_ * 4;            //  1 MB
    float* Hc     = (float*)ws;  ws += (size_t)B_ * NC_ * D_ * 4;            //  1 MB
    float* hstart = (float*)ws;                                              //  1 MB

    prep_kernel<<<2048, 256, 0, stream>>>(
        (const float4*)x, (const float4*)Wr, (const float4*)Wi, lam,
        (ushort4*)xb, (ushort4*)wrb, (ushort4*)wib, decay);

    gemm_gates<<<dim3(BT_ / BMR, D_ / BNC), 512, 0, stream>>>(
        xb, wrb, wib, br, bi, decay, x, a_buf, out);

    scan1<<<(B_ * NC_ * D_) / 256, 256, 0, stream>>>(a_buf, out, P, Hc);

    combine<<<(B_ * D_) / 256, 256, 0, stream>>>(P, Hc, h0, hstart, out + (size_t)BT_ * D_);

    scan2<<<(B_ * NC_ * D_) / 256, 256, 0, stream>>>(a_buf, out, hstart);
}

// Round 5
// 137.606 us; speedup vs baseline: 4.3590x; 1.2112x over previous
//
#include <hip/hip_runtime.h>

// RG-LRU fused kernel set for MI355X (gfx950)
// B=4, T=4096, D=1024
// R5: traffic restructure on top of R4's 8-phase GEMM:
//   - epilogue packs (a,gx) as fp16x2 in one u32 -> 67 MB instead of 134 MB
//   - scan1 fused into gemm epilogue via post-loop LDS stash (chunk P,H computed
//     in-block); scan1 kernel deleted
//   - epilogue reads xb (bf16) not x (fp32); scan2 reads packed ag

#define B_ 4
#define T_ 4096
#define D_ 1024
#define BT_ (B_ * T_)          // 16384
#define NC_ 64                 // chunks over T
#define L_ (T_ / NC_)          // 64 steps per chunk

#define BMR 256                // M rows per block
#define BNC 128                // d cols per block
#define BKT 64                 // K per tile
#define NT_ (D_ / BKT)         // 16 K-tiles
#define BUFB 65536             // bytes per LDS buffer (A 32K + B 32K)
#define STASH_STRIDE 132       // words per stash row (128 + 4 pad: <=2-way banks)

typedef float v4f __attribute__((ext_vector_type(4)));
typedef __bf16 v8bf __attribute__((ext_vector_type(8)));
typedef unsigned int u32;

__device__ inline unsigned short f2bf(float f) {
    unsigned int u = __float_as_uint(f);
    u += 0x7FFFu + ((u >> 16) & 1u);   // round-to-nearest-even
    return (unsigned short)(u >> 16);
}

__device__ inline ushort4 f2bf4(float4 v) {
    return make_ushort4(f2bf(v.x), f2bf(v.y), f2bf(v.z), f2bf(v.w));
}

__device__ inline u32 pack_ag(float a, float g) {
    _Float16 ah = (_Float16)a, gh = (_Float16)g;
    unsigned short au, gu;
    __builtin_memcpy(&au, &ah, 2);
    __builtin_memcpy(&gu, &gh, 2);
    return ((u32)gu << 16) | au;
}
__device__ inline float unpack_a(u32 v) {
    unsigned short u = (unsigned short)(v & 0xffffu);
    _Float16 h; __builtin_memcpy(&h, &u, 2); return (float)h;
}
__device__ inline float unpack_g(u32 v) {
    unsigned short u = (unsigned short)(v >> 16);
    _Float16 h; __builtin_memcpy(&h, &u, 2); return (float)h;
}
__device__ inline float bf2f(unsigned short u) {
    return __uint_as_float((u32)u << 16);
}

// async global->LDS, 16B per lane; lds base must be wave-uniform
__device__ inline void gload16(const void* g, void* l) {
    __builtin_amdgcn_global_load_lds(
        (const __attribute__((address_space(1))) u32*)g,
        (__attribute__((address_space(3))) u32*)l, 16, 0, 0);
}

// ---------------------------------------------------------------- prep
__global__ void prep_kernel(const float4* __restrict__ x4,
                            const float4* __restrict__ wr4,
                            const float4* __restrict__ wi4,
                            const float* __restrict__ lam,
                            ushort4* __restrict__ xb4,
                            ushort4* __restrict__ wrb4,
                            ushort4* __restrict__ wib4,
                            float* __restrict__ decay) {
    const int n = gridDim.x * blockDim.x;
    const int tid = blockIdx.x * blockDim.x + threadIdx.x;
    const int nx4 = (BT_ * D_) / 4;
    const int nw4 = (D_ * D_) / 4;
    for (int i = tid; i < nx4; i += n) xb4[i] = f2bf4(x4[i]);
    for (int i = tid; i < nw4; i += n) {
        wrb4[i] = f2bf4(wr4[i]);
        wib4[i] = f2bf4(wi4[i]);
    }
    for (int i = tid; i < D_; i += n) {
        float sp = log1pf(expf(lam[i]));
        decay[i] = 8.0f * sp;
    }
}

// ---------------------------------------------------------------- gemm + gates + chunk-scan
__global__ __launch_bounds__(512, 2) void gemm_gates(
    const unsigned short* __restrict__ xb,
    const unsigned short* __restrict__ wrb,
    const unsigned short* __restrict__ wib,
    const float* __restrict__ br,
    const float* __restrict__ bi,
    const float* __restrict__ decay,
    u32* __restrict__ ag,
    float* __restrict__ P,
    float* __restrict__ H) {
    // loop uses [0, 131072); post-loop stash uses [0, 256*132*4 = 135168)
    __shared__ __align__(16) char lds[256 * STASH_STRIDE * 4];

    const int tid = threadIdx.x;
    const int lane = tid & 63;
    const int wave = tid >> 6;      // 0..7
    const int wr = wave >> 2;       // 0..1
    const int wc = wave & 3;        // 0..3
    const int lr = lane & 15;
    const int lg = lane >> 4;
    const int rowbase = blockIdx.x * BMR;
    const int colbase = blockIdx.y * BNC;

    // staging map: thread covers one 16B piece per gload16 issue
    const int srow = tid >> 3;                    // 0..63 within quarter
    const int kslot = (tid & 7) ^ (srow & 7);     // pre-swizzled global slot

    const unsigned short* gAq[4];
#pragma unroll
    for (int q = 0; q < 4; ++q)
        gAq[q] = xb + (size_t)(rowbase + q * 64 + srow) * D_ + kslot * 8;
    const unsigned short* gBq[4];
    gBq[0] = wrb + (size_t)(colbase + srow) * D_ + kslot * 8;
    gBq[1] = wib + (size_t)(colbase + srow) * D_ + kslot * 8;
    gBq[2] = wrb + (size_t)(colbase + 64 + srow) * D_ + kslot * 8;
    gBq[3] = wib + (size_t)(colbase + 64 + srow) * D_ + kslot * 8;

#define STG_A(nb, q, kel) gload16(gAq[q] + (kel), lds + (nb) * BUFB + (q) * 8192 + wave * 1024)
#define STG_B(nb, q, kel) gload16(gBq[q] + (kel), lds + (nb) * BUFB + 32768 + (q) * 8192 + wave * 1024)

    const int bo = (wc & 1) * 32;       // within-strip col offset
    const int bstrip = wc >> 1;         // d-strip (0: d0..63, 1: d64..127)

    v4f ar[8][2], ai[8][2];
#pragma unroll
    for (int mi = 0; mi < 8; ++mi)
#pragma unroll
        for (int nf = 0; nf < 2; ++nf)
#pragma unroll
            for (int j = 0; j < 4; ++j) { ar[mi][nf][j] = 0.0f; ai[mi][nf][j] = 0.0f; }

    v8bf cbr[2], cbi[2];   // B fragments, persist MH0 -> MH1

    // ---- prologue: stage tile 0 into buf 0, full drain
    STG_A(0, 0, 0); STG_A(0, 1, 0); STG_A(0, 2, 0); STG_A(0, 3, 0);
    STG_B(0, 0, 0); STG_B(0, 1, 0); STG_B(0, 2, 0); STG_B(0, 3, 0);
    __builtin_amdgcn_sched_barrier(0);
    asm volatile("s_waitcnt vmcnt(0)");
    __builtin_amdgcn_s_barrier();

#define PHASE(lb, KS, MH, PRECODE)                                              \
    do {                                                                        \
        if ((MH) == 0) {                                                        \
            _Pragma("unroll")                                                   \
            for (int nf = 0; nf < 2; ++nf) {                                    \
                const int brr = bstrip * 128 + bo + nf * 16 + lr;               \
                cbr[nf] = *(const v8bf*)((lb) + 32768 + brr * 128 +             \
                                         (((KS) * 4 + lg) ^ (brr & 7)) * 16);   \
                const int bri = brr + 64;                                       \
                cbi[nf] = *(const v8bf*)((lb) + 32768 + bri * 128 +             \
                                         (((KS) * 4 + lg) ^ (bri & 7)) * 16);   \
            }                                                                   \
        }                                                                       \
        v8bf af[4];                                                             \
        _Pragma("unroll")                                                       \
        for (int m4 = 0; m4 < 4; ++m4) {                                        \
            const int row = wr * 128 + ((MH) * 4 + m4) * 16 + lr;               \
            af[m4] = *(const v8bf*)((lb) + row * 128 +                          \
                                    (((KS) * 4 + lg) ^ (row & 7)) * 16);        \
        }                                                                       \
        PRECODE;                                                                \
        __builtin_amdgcn_sched_barrier(0);                                      \
        __builtin_amdgcn_s_barrier();                                           \
        __builtin_amdgcn_s_setprio(1);                                          \
        _Pragma("unroll")                                                       \
        for (int m4 = 0; m4 < 4; ++m4)                                          \
            _Pragma("unroll")                                                   \
            for (int nf = 0; nf < 2; ++nf) {                                    \
                ar[(MH) * 4 + m4][nf] = __builtin_amdgcn_mfma_f32_16x16x32_bf16( \
                    af[m4], cbr[nf], ar[(MH) * 4 + m4][nf], 0, 0, 0);           \
                ai[(MH) * 4 + m4][nf] = __builtin_amdgcn_mfma_f32_16x16x32_bf16( \
                    af[m4], cbi[nf], ai[(MH) * 4 + m4][nf], 0, 0, 0);           \
            }                                                                   \
        __builtin_amdgcn_s_setprio(0);                                          \
        __builtin_amdgcn_sched_barrier(0);                                      \
        __builtin_amdgcn_s_barrier();                                           \
    } while (0)

    for (int t = 0; t < NT_; ++t) {
        const int sw = t & 1;
        const int nb = sw ^ 1;
        const char* lb = lds + sw * BUFB;
        const int knext = (t + 1) * BKT;
        const bool more = (t + 1 < NT_);

        PHASE(lb, 0, 0,
              if (more) {
                  STG_B(nb, 0, knext); STG_B(nb, 1, knext);
                  __builtin_amdgcn_sched_barrier(0);
                  asm volatile("s_waitcnt vmcnt(2)");
              } else {
                  __builtin_amdgcn_sched_barrier(0);
                  asm volatile("s_waitcnt vmcnt(0)");
              });
        PHASE(lb, 0, 1,
              if (more) { STG_B(nb, 2, knext); STG_B(nb, 3, knext); });
        PHASE(lb, 1, 0,
              if (more) { STG_A(nb, 0, knext); STG_A(nb, 2, knext); });
        PHASE(lb, 1, 1,
              if (more) {
                  STG_A(nb, 1, knext); STG_A(nb, 3, knext);
                  __builtin_amdgcn_sched_barrier(0);
                  asm volatile("s_waitcnt vmcnt(2)");
              });
    }
#undef PHASE
#undef STG_A
#undef STG_B

    // ---- fused gate epilogue: pack (a,gx) fp16x2 -> global ag + LDS stash
#pragma unroll
    for (int nf = 0; nf < 2; ++nf) {
        const int gcol = colbase + wc * 32 + nf * 16 + lr;
        const float brv = br[gcol];
        const float biv = bi[gcol];
        const float dec = decay[gcol];
#pragma unroll
        for (int mi = 0; mi < 8; ++mi) {
#pragma unroll
            for (int rr = 0; rr < 4; ++rr) {
                const int rl = wr * 128 + mi * 16 + lg * 4 + rr;   // 0..255
                const int grow = rowbase + rl;
                const size_t o = (size_t)grow * D_ + gcol;
                const float zr = ar[mi][nf][rr] + brv;
                const float zi = ai[mi][nf][rr] + biv;
                const float rg = 1.0f / (1.0f + __expf(-zr));
                const float ig = 1.0f / (1.0f + __expf(-zi));
                const float av = __expf(-dec * rg);
                const float sc = sqrtf(fmaxf(1.0f - av * av, 0.0f));
                const float xv = bf2f(xb[o]);
                const float gv = sc * (ig * xv);
                const u32 pk = pack_ag(av, gv);
                ag[o] = pk;
                const int cl = wc * 32 + nf * 16 + lr;             // 0..127
                *(u32*)(lds + (size_t)(rl * STASH_STRIDE + cl) * 4) = pk;
            }
        }
    }
    __syncthreads();

    // ---- fused scan1: 4 chunks x 128 cols; thread -> one (chunk, col)
    {
        const int c = tid >> 7;          // 0..3
        const int j = tid & 127;         // 0..127
        const char* sb = lds + (size_t)(c * 64 * STASH_STRIDE + j) * 4;
        float p = 1.0f, h = 0.0f;
#pragma unroll 8
        for (int t = 0; t < 64; ++t) {
            const u32 v = *(const u32*)(sb + (size_t)t * STASH_STRIDE * 4);
            const float a_ = unpack_a(v);
            const float g_ = unpack_g(v);
            p *= a_;
            h = a_ * h + g_;
        }
        const int gc = (rowbase >> 6) + c;     // global chunk id = flatrow/64
        P[(size_t)gc * D_ + colbase + j] = p;
        H[(size_t)gc * D_ + colbase + j] = h;
    }
}

// ---------------------------------------------------------------- combine
__global__ __launch_bounds__(256) void combine(const float* __restrict__ P,
                                               const float* __restrict__ H,
                                               const float* __restrict__ h0,
                                               float* __restrict__ hstart,
                                               float* __restrict__ hT) {
    const int idx = blockIdx.x * 256 + threadIdx.x;   // [0, B*D)
    const int d = idx & (D_ - 1);
    const int b = idx >> 10;
    float h = h0[b * D_ + d];
    for (int c = 0; c < NC_; ++c) {
        const int o = (b * NC_ + c) * D_ + d;
        hstart[o] = h;
        h = P[o] * h + H[o];
    }
    hT[b * D_ + d] = h;
}

// ---------------------------------------------------------------- scan pass 2
__global__ __launch_bounds__(256) void scan2(const u32* __restrict__ ag,
                                             float* __restrict__ out,
                                             const float* __restrict__ hstart) {
    const int idx = blockIdx.x * 256 + threadIdx.x;   // [0, B*NC*D)
    const int d = idx & (D_ - 1);
    const int c = (idx >> 10) & (NC_ - 1);
    const int b = idx >> 16;
    const size_t base = ((size_t)b * T_ + c * L_) * D_ + d;
    float h = hstart[idx];
#pragma unroll 4
    for (int t = 0; t < L_; ++t) {
        const size_t o = base + (size_t)t * D_;
        const u32 v = ag[o];
        h = unpack_a(v) * h + unpack_g(v);
        out[o] = h;
    }
}

// ---------------------------------------------------------------- launch
extern "C" void kernel_launch(void* const* d_in, const int* in_sizes, int n_in,
                              void* d_out, int out_size, void* d_ws, size_t ws_size,
                              hipStream_t stream) {
    const float* x   = (const float*)d_in[0];
    const float* h0  = (const float*)d_in[1];
    const float* Wr  = (const float*)d_in[2];
    const float* br  = (const float*)d_in[3];
    const float* Wi  = (const float*)d_in[4];
    const float* bi  = (const float*)d_in[5];
    const float* lam = (const float*)d_in[6];
    float* out = (float*)d_out;

    char* ws = (char*)d_ws;
    unsigned short* xb  = (unsigned short*)ws; ws += (size_t)BT_ * D_ * 2;   // 33.5 MB
    unsigned short* wrb = (unsigned short*)ws; ws += (size_t)D_ * D_ * 2;    //  2 MB
    unsigned short* wib = (unsigned short*)ws; ws += (size_t)D_ * D_ * 2;    //  2 MB
    float* decay  = (float*)ws;  ws += (size_t)D_ * 4;                       //  4 KB
    u32* ag       = (u32*)ws;    ws += (size_t)BT_ * D_ * 4;                 // 67 MB
    float* P      = (float*)ws;  ws += (size_t)B_ * NC_ * D_ * 4;            //  1 MB
    float* Hc     = (float*)ws;  ws += (size_t)B_ * NC_ * D_ * 4;            //  1 MB
    float* hstart = (float*)ws;                                              //  1 MB

    prep_kernel<<<2048, 256, 0, stream>>>(
        (const float4*)x, (const float4*)Wr, (const float4*)Wi, lam,
        (ushort4*)xb, (ushort4*)wrb, (ushort4*)wib, decay);

    gemm_gates<<<dim3(BT_ / BMR, D_ / BNC), 512, 0, stream>>>(
        xb, wrb, wib, br, bi, decay, ag, P, Hc);

    combine<<<(B_ * D_) / 256, 256, 0, stream>>>(P, Hc, h0, hstart, out + (size_t)BT_ * D_);

    scan2<<<(B_ * NC_ * D_) / 256, 256, 0, stream>>>(ag, out, hstart);
}